// Round 4
// baseline (178.444 us; speedup 1.0000x reference)
//
#include <hip/hip_runtime.h>
#include <math.h>

#define MU_MAXC 32
#define MV_MAXC 32
#define OUT_UC  64
#define OUT_VC  64
#define DEG     3
#define NKNOT   (MU_MAXC + DEG + 1)   // 36
#define EPSV    1e-5f

__global__ void zero_ws_kernel(double* acc, int* bad) {
    acc[0] = 0.0; acc[1] = 0.0; acc[2] = 0.0; bad[0] = 0;
}

// MODE 0: per-block partials  pd[b], pd[B+b], pd[2B+b], badp[b]
// MODE 1: atomic fallback (only if ws too small)
template <int MODE>
__launch_bounds__(256, 5)
__global__ void nurbs_loss_kernel(const float* __restrict__ ctrl_pred,
                                  const float* __restrict__ ctrl_gt,
                                  const float* __restrict__ mask,
                                  const float* __restrict__ xyz,
                                  double* __restrict__ pd, int Bcnt,
                                  int* __restrict__ badp)
{
    const int b   = blockIdx.x;
    const int tid = threadIdx.x;

    __shared__ float s_tmp[OUT_UC * MV_MAXC * 3];    // 24 KB [u][j][d]
    __shared__ float s_mask[1024];                   // 4 KB
    __shared__ float s_Bu4[4 * OUT_UC];              // SoA [r][u]
    __shared__ float s_Bv4[4 * OUT_VC];              // SoA [r][v], pre-divided by sumBv
    __shared__ int   s_uoff[OUT_UC];
    __shared__ int   s_voff[OUT_VC];
    __shared__ float s_invSumBu[OUT_UC];
    __shared__ float s_knots_u[NKNOT];
    __shared__ float s_knots_v[NKNOT];
    __shared__ int   s_rowany[MU_MAXC];
    __shared__ int   s_colany[MV_MAXC];
    __shared__ int   s_mu, s_mv, s_bad;
    __shared__ float s_wred[4], s_wred2[4];
    __shared__ float s_ctrl_diff, s_ctrl_mask;

    if (tid < 32) { s_rowany[tid] = 0; s_colany[tid] = 0; }
    if (tid == 0) s_bad = 0;
    __syncthreads();

    // ---- Phase A1: stage mask to LDS, mask-sum + row/col-any flags ----
    float lsum_mask = 0.f;
    #pragma unroll
    for (int k = 0; k < 4; k++) {
        const int cell = tid + 256 * k;               // i*32+j
        const float m  = mask[b * 1024 + cell];
        s_mask[cell] = m;
        lsum_mask += m;
        if (m > 0.f) { s_rowany[cell >> 5] = 1; s_colany[cell & 31] = 1; }
    }
    __syncthreads();

    // ---- Phase A2: vectorized masked ctrl MSE (float4 over 3072 floats) ----
    float lsum_diff = 0.f;
    {
        const float4* p4 = (const float4*)(ctrl_pred + (size_t)b * 3072);
        const float4* g4 = (const float4*)(ctrl_gt   + (size_t)b * 3072);
        #pragma unroll
        for (int k = 0; k < 3; k++) {
            const int e4 = tid + 256 * k;             // < 768
            const float4 p = p4[e4];
            const float4 g = g4[e4];
            const int e = e4 * 4;
            const float dx = p.x - g.x, dy = p.y - g.y, dz = p.z - g.z, dw = p.w - g.w;
            lsum_diff += s_mask[(e + 0) / 3] * dx * dx
                       + s_mask[(e + 1) / 3] * dy * dy
                       + s_mask[(e + 2) / 3] * dz * dz
                       + s_mask[(e + 3) / 3] * dw * dw;
        }
    }
    #pragma unroll
    for (int off = 32; off > 0; off >>= 1) {
        lsum_mask += __shfl_down(lsum_mask, off);
        lsum_diff += __shfl_down(lsum_diff, off);
    }
    if ((tid & 63) == 0) { s_wred[tid >> 6] = lsum_mask; s_wred2[tid >> 6] = lsum_diff; }
    __syncthreads();

    if (tid == 0) {
        int cu = 0, cv = 0;
        #pragma unroll
        for (int i = 0; i < 32; i++) { cu += s_rowany[i]; cv += s_colany[i]; }
        s_mu = cu > (DEG + 1) ? cu : (DEG + 1);
        s_mv = cv > (DEG + 1) ? cv : (DEG + 1);
        s_ctrl_mask = s_wred[0] + s_wred[1] + s_wred[2] + s_wred[3];
        s_ctrl_diff = s_wred2[0] + s_wred2[1] + s_wred2[2] + s_wred2[3];
    }
    __syncthreads();

    // ---- Phase B: clamped open-uniform knots (padded entries -> 1.0) ----
    if (tid < NKNOT) {
        const int L = s_mu + DEG + 1;
        s_knots_u[tid] = (tid <= DEG) ? 0.f
                        : ((tid >= L - 1 - DEG) ? 1.f : (float)tid / (float)(L - 1));
    } else if (tid >= 64 && tid < 64 + NKNOT) {
        const int k = tid - 64;
        const int L = s_mv + DEG + 1;
        s_knots_v[k] = (k <= DEG) ? 0.f
                      : ((k >= L - 1 - DEG) ? 1.f : (float)k / (float)(L - 1));
    }
    __syncthreads();

    // ---- Phase C: span-based Cox-de Boor (4 nonzero weights) ----
    if (tid < 128) {
        const bool isU = tid < 64;
        const int t = isU ? tid : (tid - 64);
        const float* kv = isU ? s_knots_u : s_knots_v;
        const float step = (1.f - 2.f * EPSV) / 63.f;
        const float uu = (t == 63) ? (1.f - EPSV) : (EPSV + step * (float)t);

        int span = DEG;
        #pragma unroll
        for (int k = DEG + 1; k < NKNOT - 1; k++)
            if (kv[k] <= uu) span = k;

        float N4[DEG + 1], left[DEG + 1], right[DEG + 1];
        N4[0] = 1.f;
        #pragma unroll
        for (int j = 1; j <= DEG; j++) {
            left[j]  = uu - kv[span + 1 - j];
            right[j] = kv[span + j] - uu;
            float saved = 0.f;
            #pragma unroll
            for (int r = 0; r < j; r++) {
                const float temp = N4[r] / (right[r + 1] + left[j - r]);
                N4[r] = saved + right[r + 1] * temp;
                saved = left[j - r] * temp;
            }
            N4[j] = saved;
        }
        const float s = N4[0] + N4[1] + N4[2] + N4[3];
        const float invs = 1.0f / s;
        const int off = span - DEG;                   // in [0, 28]
        if (isU) {
            #pragma unroll
            for (int r = 0; r < 4; r++) s_Bu4[r * 64 + t] = N4[r];
            s_uoff[t] = off; s_invSumBu[t] = invs;
        } else {
            #pragma unroll
            for (int r = 0; r < 4; r++) s_Bv4[r * 64 + t] = N4[r] * invs;  // fold 1/sumBv
            s_voff[t] = off;
        }
    }
    __syncthreads();

    // ---- Phase C2 (float4): tmp row u = sum_{r<4} Bu4[r][u] * ctrl row (uoff+r)
    //      each row is 96 floats = 24 float4; flat4 = u*24 + q, 1536 total ----
    {
        const float4* ctrl4 = (const float4*)(ctrl_pred + (size_t)b * 3072);
        float4* tmp4 = (float4*)s_tmp;
        #pragma unroll
        for (int k = 0; k < 6; k++) {
            const int flat4 = tid + 256 * k;          // < 1536
            const int u = flat4 / 24;
            const int q = flat4 - u * 24;
            const int off = s_uoff[u];
            const float w0 = s_Bu4[0 * 64 + u];
            const float w1 = s_Bu4[1 * 64 + u];
            const float w2 = s_Bu4[2 * 64 + u];
            const float w3 = s_Bu4[3 * 64 + u];
            const float4 c0 = ctrl4[(off + 0) * 24 + q];
            const float4 c1 = ctrl4[(off + 1) * 24 + q];
            const float4 c2 = ctrl4[(off + 2) * 24 + q];
            const float4 c3 = ctrl4[(off + 3) * 24 + q];
            float4 a;
            a.x = w0 * c0.x + w1 * c1.x + w2 * c2.x + w3 * c3.x;
            a.y = w0 * c0.y + w1 * c1.y + w2 * c2.y + w3 * c3.y;
            a.z = w0 * c0.z + w1 * c1.z + w2 * c2.z + w3 * c3.z;
            a.w = w0 * c0.w + w1 * c1.w + w2 * c2.w + w3 * c3.w;
            tmp4[flat4] = a;
        }
    }
    __syncthreads();

    // ---- Phase D: surf eval + squared error vs xyz ----
    float lsum_surf = 0.f;
    int bad = 0;
    {
        const int v = tid & 63;
        const int voff3 = s_voff[v] * 3;
        const float w0 = s_Bv4[0 * 64 + v];
        const float w1 = s_Bv4[1 * 64 + v];
        const float w2 = s_Bv4[2 * 64 + v];
        const float w3 = s_Bv4[3 * 64 + v];
        #pragma unroll
        for (int k = 0; k < 16; k++) {
            const int u = (tid >> 6) + 4 * k;
            const float* tp = &s_tmp[u * 96 + voff3];
            const float n0 = w0 * tp[0] + w1 * tp[3] + w2 * tp[6] + w3 * tp[9];
            const float n1 = w0 * tp[1] + w1 * tp[4] + w2 * tp[7] + w3 * tp[10];
            const float n2 = w0 * tp[2] + w1 * tp[5] + w2 * tp[8] + w3 * tp[11];
            const float inv = s_invSumBu[u];          // broadcast read
            const float x0 = n0 * inv, x1 = n1 * inv, x2 = n2 * inv;
            const int base = (b * 4096 + u * 64 + v) * 3;
            const float d0 = x0 - xyz[base + 0];
            const float d1 = x1 - xyz[base + 1];
            const float d2 = x2 - xyz[base + 2];
            lsum_surf += d0 * d0 + d1 * d1 + d2 * d2;
            if (!isfinite(x0) || !isfinite(x1) || !isfinite(x2)) bad = 1;
        }
    }
    #pragma unroll
    for (int off = 32; off > 0; off >>= 1)
        lsum_surf += __shfl_down(lsum_surf, off);
    if ((tid & 63) == 0) s_wred[tid >> 6] = lsum_surf;
    if (bad) atomicOr(&s_bad, 1);
    __syncthreads();

    if (tid == 0) {
        const double surf = (double)s_wred[0] + s_wred[1] + s_wred[2] + s_wred[3];
        if (MODE == 0) {
            pd[b]             = (double)s_ctrl_diff;
            pd[Bcnt + b]      = (double)s_ctrl_mask;
            pd[2 * Bcnt + b]  = surf;
            badp[b]           = s_bad;
        } else {
            atomicAdd(&pd[0], (double)s_ctrl_diff);
            atomicAdd(&pd[1], (double)s_ctrl_mask);
            atomicAdd(&pd[2], surf);
            if (s_bad) atomicOr(badp, 1);
        }
    }
}

__global__ void finalize_partials_kernel(const double* __restrict__ pd,
                                         const int* __restrict__ badp,
                                         float* __restrict__ out, int Bcnt)
{
    __shared__ double sd0[4], sd1[4], sd2[4];
    __shared__ int sb[4];
    const int tid = threadIdx.x;
    double a0 = 0.0, a1 = 0.0, a2 = 0.0; int bad = 0;
    for (int i = tid; i < Bcnt; i += 256) {
        a0 += pd[i]; a1 += pd[Bcnt + i]; a2 += pd[2 * Bcnt + i];
        bad |= badp[i];
    }
    #pragma unroll
    for (int off = 32; off > 0; off >>= 1) {
        a0 += __shfl_down(a0, off);
        a1 += __shfl_down(a1, off);
        a2 += __shfl_down(a2, off);
        bad |= __shfl_down(bad, off);
    }
    if ((tid & 63) == 0) { const int w = tid >> 6; sd0[w] = a0; sd1[w] = a1; sd2[w] = a2; sb[w] = bad; }
    __syncthreads();
    if (tid == 0) {
        double d0 = 0, d1 = 0, d2 = 0; int bb = 0;
        #pragma unroll
        for (int i = 0; i < 4; i++) { d0 += sd0[i]; d1 += sd1[i]; d2 += sd2[i]; bb |= sb[i]; }
        const double denc = d1 * 3.0;
        const double lc = d0 / (denc > 1.0 ? denc : 1.0);
        const double ls = d2 / ((double)Bcnt * OUT_UC * OUT_VC * 3.0);
        out[0] = (float)(lc + ls);            // total (pre-nan-guard, per ref)
        out[1] = (float)lc;                   // loss_ctrl
        out[2] = bb ? 1.0e6f : (float)ls;     // surf_mse with nan/inf guard
    }
}

__global__ void finalize_atomic_kernel(const double* __restrict__ acc,
                                       const int* __restrict__ bad,
                                       float* __restrict__ out, int Bcnt)
{
    const double denc = acc[1] * 3.0;
    const double lc = acc[0] / (denc > 1.0 ? denc : 1.0);
    const double ls = acc[2] / ((double)Bcnt * OUT_UC * OUT_VC * 3.0);
    out[0] = (float)(lc + ls);
    out[1] = (float)lc;
    out[2] = bad[0] ? 1.0e6f : (float)ls;
}

extern "C" void kernel_launch(void* const* d_in, const int* in_sizes, int n_in,
                              void* d_out, int out_size, void* d_ws, size_t ws_size,
                              hipStream_t stream)
{
    const float* pred = (const float*)d_in[0];
    const float* gt   = (const float*)d_in[1];
    const float* mask = (const float*)d_in[2];
    const float* xyz  = (const float*)d_in[3];
    const int Bcnt = in_sizes[2] / (MU_MAXC * MV_MAXC);   // 1024

    double* pd = (double*)d_ws;
    float* out = (float*)d_out;

    const size_t need = (size_t)3 * Bcnt * sizeof(double) + (size_t)Bcnt * sizeof(int);
    if (ws_size >= need) {
        int* badp = (int*)(pd + 3 * Bcnt);
        hipLaunchKernelGGL((nurbs_loss_kernel<0>), dim3(Bcnt), dim3(256), 0, stream,
                           pred, gt, mask, xyz, pd, Bcnt, badp);
        hipLaunchKernelGGL(finalize_partials_kernel, dim3(1), dim3(256), 0, stream,
                           pd, badp, out, Bcnt);
    } else {
        int* badp = (int*)(pd + 3);
        hipLaunchKernelGGL(zero_ws_kernel, dim3(1), dim3(1), 0, stream, pd, badp);
        hipLaunchKernelGGL((nurbs_loss_kernel<1>), dim3(Bcnt), dim3(256), 0, stream,
                           pred, gt, mask, xyz, pd, Bcnt, badp);
        hipLaunchKernelGGL(finalize_atomic_kernel, dim3(1), dim3(1), 0, stream,
                           pd, badp, out, Bcnt);
    }
}

// Round 5
// 113.756 us; speedup vs baseline: 1.5687x; 1.5687x over previous
//
#include <hip/hip_runtime.h>
#include <math.h>

#define MU_MAXC 32
#define MV_MAXC 32
#define OUT_UC  64
#define OUT_VC  64
#define DEG     3
#define NKNOT   (MU_MAXC + DEG + 1)   // 36
#define EPSV    1e-5f

__global__ void zero_ws_kernel(double* acc, int* bad) {
    acc[0] = 0.0; acc[1] = 0.0; acc[2] = 0.0; bad[0] = 0;
}

// MODE 0: per-block partials  pd[b], pd[B+b], pd[2B+b], badp[b]
// MODE 1: atomic fallback (only if ws too small)
// NOTE: no min-waves arg — LDS (32 KB) already caps blocks/CU; a VGPR cap
// caused 130 MB of scratch spills in R3 (VGPR 48, 2.4x regression).
template <int MODE>
__launch_bounds__(256)
__global__ void nurbs_loss_kernel(const float* __restrict__ ctrl_pred,
                                  const float* __restrict__ ctrl_gt,
                                  const float* __restrict__ mask,
                                  const float* __restrict__ xyz,
                                  double* __restrict__ pd, int Bcnt,
                                  int* __restrict__ badp)
{
    const int b   = blockIdx.x;
    const int tid = threadIdx.x;

    __shared__ float s_tmp[OUT_UC * MV_MAXC * 3];    // 24 KB [u][j][d]
    __shared__ float s_mask[1024];                   // 4 KB
    __shared__ float s_Bu4[4 * OUT_UC];              // SoA [r][u]
    __shared__ float s_Bv4[4 * OUT_VC];              // SoA [r][v], pre-divided by sumBv
    __shared__ int   s_uoff[OUT_UC];
    __shared__ int   s_voff[OUT_VC];
    __shared__ float s_invSumBu[OUT_UC];
    __shared__ float s_knots_u[NKNOT];
    __shared__ float s_knots_v[NKNOT];
    __shared__ int   s_rowany[MU_MAXC];
    __shared__ int   s_colany[MV_MAXC];
    __shared__ int   s_mu, s_mv, s_bad;
    __shared__ float s_wred[4], s_wred2[4];
    __shared__ float s_ctrl_diff, s_ctrl_mask;

    if (tid < 32) { s_rowany[tid] = 0; s_colany[tid] = 0; }
    if (tid == 0) s_bad = 0;
    __syncthreads();

    // ---- Phase A1: stage mask to LDS, mask-sum + row/col-any flags ----
    float lsum_mask = 0.f;
    #pragma unroll
    for (int k = 0; k < 4; k++) {
        const int cell = tid + 256 * k;               // i*32+j
        const float m  = mask[b * 1024 + cell];
        s_mask[cell] = m;
        lsum_mask += m;
        if (m > 0.f) { s_rowany[cell >> 5] = 1; s_colany[cell & 31] = 1; }
    }
    __syncthreads();

    // ---- Phase A2: vectorized masked ctrl MSE (float4 over 3072 floats) ----
    float lsum_diff = 0.f;
    {
        const float4* p4 = (const float4*)(ctrl_pred + (size_t)b * 3072);
        const float4* g4 = (const float4*)(ctrl_gt   + (size_t)b * 3072);
        #pragma unroll
        for (int k = 0; k < 3; k++) {
            const int e4 = tid + 256 * k;             // < 768
            const float4 p = p4[e4];
            const float4 g = g4[e4];
            const int e = e4 * 4;
            const float dx = p.x - g.x, dy = p.y - g.y, dz = p.z - g.z, dw = p.w - g.w;
            lsum_diff += s_mask[(e + 0) / 3] * dx * dx
                       + s_mask[(e + 1) / 3] * dy * dy
                       + s_mask[(e + 2) / 3] * dz * dz
                       + s_mask[(e + 3) / 3] * dw * dw;
        }
    }
    #pragma unroll
    for (int off = 32; off > 0; off >>= 1) {
        lsum_mask += __shfl_down(lsum_mask, off);
        lsum_diff += __shfl_down(lsum_diff, off);
    }
    if ((tid & 63) == 0) { s_wred[tid >> 6] = lsum_mask; s_wred2[tid >> 6] = lsum_diff; }
    __syncthreads();

    if (tid == 0) {
        int cu = 0, cv = 0;
        #pragma unroll
        for (int i = 0; i < 32; i++) { cu += s_rowany[i]; cv += s_colany[i]; }
        s_mu = cu > (DEG + 1) ? cu : (DEG + 1);
        s_mv = cv > (DEG + 1) ? cv : (DEG + 1);
        s_ctrl_mask = s_wred[0] + s_wred[1] + s_wred[2] + s_wred[3];
        s_ctrl_diff = s_wred2[0] + s_wred2[1] + s_wred2[2] + s_wred2[3];
    }
    __syncthreads();

    // ---- Phase B: clamped open-uniform knots (padded entries -> 1.0) ----
    if (tid < NKNOT) {
        const int L = s_mu + DEG + 1;
        s_knots_u[tid] = (tid <= DEG) ? 0.f
                        : ((tid >= L - 1 - DEG) ? 1.f : (float)tid / (float)(L - 1));
    } else if (tid >= 64 && tid < 64 + NKNOT) {
        const int k = tid - 64;
        const int L = s_mv + DEG + 1;
        s_knots_v[k] = (k <= DEG) ? 0.f
                      : ((k >= L - 1 - DEG) ? 1.f : (float)k / (float)(L - 1));
    }
    __syncthreads();

    // ---- Phase C: span-based Cox-de Boor (4 nonzero weights) ----
    if (tid < 128) {
        const bool isU = tid < 64;
        const int t = isU ? tid : (tid - 64);
        const float* kv = isU ? s_knots_u : s_knots_v;
        const float step = (1.f - 2.f * EPSV) / 63.f;
        const float uu = (t == 63) ? (1.f - EPSV) : (EPSV + step * (float)t);

        int span = DEG;
        #pragma unroll
        for (int k = DEG + 1; k < NKNOT - 1; k++)
            if (kv[k] <= uu) span = k;

        float N4[DEG + 1], left[DEG + 1], right[DEG + 1];
        N4[0] = 1.f;
        #pragma unroll
        for (int j = 1; j <= DEG; j++) {
            left[j]  = uu - kv[span + 1 - j];
            right[j] = kv[span + j] - uu;
            float saved = 0.f;
            #pragma unroll
            for (int r = 0; r < j; r++) {
                const float temp = N4[r] / (right[r + 1] + left[j - r]);
                N4[r] = saved + right[r + 1] * temp;
                saved = left[j - r] * temp;
            }
            N4[j] = saved;
        }
        const float s = N4[0] + N4[1] + N4[2] + N4[3];
        const float invs = 1.0f / s;
        const int off = span - DEG;                   // in [0, 28]
        if (isU) {
            #pragma unroll
            for (int r = 0; r < 4; r++) s_Bu4[r * 64 + t] = N4[r];
            s_uoff[t] = off; s_invSumBu[t] = invs;
        } else {
            #pragma unroll
            for (int r = 0; r < 4; r++) s_Bv4[r * 64 + t] = N4[r] * invs;  // fold 1/sumBv
            s_voff[t] = off;
        }
    }
    __syncthreads();

    // ---- Phase C2 (float4): tmp row u = sum_{r<4} Bu4[r][u] * ctrl row (uoff+r)
    //      each row is 96 floats = 24 float4; flat4 = u*24 + q, 1536 total ----
    {
        const float4* ctrl4 = (const float4*)(ctrl_pred + (size_t)b * 3072);
        float4* tmp4 = (float4*)s_tmp;
        for (int k = 0; k < 6; k++) {
            const int flat4 = tid + 256 * k;          // < 1536
            const int u = flat4 / 24;
            const int q = flat4 - u * 24;
            const int off = s_uoff[u];
            const float w0 = s_Bu4[0 * 64 + u];
            const float w1 = s_Bu4[1 * 64 + u];
            const float w2 = s_Bu4[2 * 64 + u];
            const float w3 = s_Bu4[3 * 64 + u];
            const float4 c0 = ctrl4[(off + 0) * 24 + q];
            const float4 c1 = ctrl4[(off + 1) * 24 + q];
            const float4 c2 = ctrl4[(off + 2) * 24 + q];
            const float4 c3 = ctrl4[(off + 3) * 24 + q];
            float4 a;
            a.x = w0 * c0.x + w1 * c1.x + w2 * c2.x + w3 * c3.x;
            a.y = w0 * c0.y + w1 * c1.y + w2 * c2.y + w3 * c3.y;
            a.z = w0 * c0.z + w1 * c1.z + w2 * c2.z + w3 * c3.z;
            a.w = w0 * c0.w + w1 * c1.w + w2 * c2.w + w3 * c3.w;
            tmp4[flat4] = a;
        }
    }
    __syncthreads();

    // ---- Phase D: surf eval + squared error vs xyz ----
    float lsum_surf = 0.f;
    int bad = 0;
    {
        const int v = tid & 63;
        const int voff3 = s_voff[v] * 3;
        const float w0 = s_Bv4[0 * 64 + v];
        const float w1 = s_Bv4[1 * 64 + v];
        const float w2 = s_Bv4[2 * 64 + v];
        const float w3 = s_Bv4[3 * 64 + v];
        #pragma unroll
        for (int k = 0; k < 16; k++) {
            const int u = (tid >> 6) + 4 * k;
            const float* tp = &s_tmp[u * 96 + voff3];
            const float n0 = w0 * tp[0] + w1 * tp[3] + w2 * tp[6] + w3 * tp[9];
            const float n1 = w0 * tp[1] + w1 * tp[4] + w2 * tp[7] + w3 * tp[10];
            const float n2 = w0 * tp[2] + w1 * tp[5] + w2 * tp[8] + w3 * tp[11];
            const float inv = s_invSumBu[u];          // broadcast read
            const float x0 = n0 * inv, x1 = n1 * inv, x2 = n2 * inv;
            const int base = (b * 4096 + u * 64 + v) * 3;
            const float d0 = x0 - xyz[base + 0];
            const float d1 = x1 - xyz[base + 1];
            const float d2 = x2 - xyz[base + 2];
            lsum_surf += d0 * d0 + d1 * d1 + d2 * d2;
            if (!isfinite(x0) || !isfinite(x1) || !isfinite(x2)) bad = 1;
        }
    }
    #pragma unroll
    for (int off = 32; off > 0; off >>= 1)
        lsum_surf += __shfl_down(lsum_surf, off);
    if ((tid & 63) == 0) s_wred[tid >> 6] = lsum_surf;
    if (bad) atomicOr(&s_bad, 1);
    __syncthreads();

    if (tid == 0) {
        const double surf = (double)s_wred[0] + s_wred[1] + s_wred[2] + s_wred[3];
        if (MODE == 0) {
            pd[b]             = (double)s_ctrl_diff;
            pd[Bcnt + b]      = (double)s_ctrl_mask;
            pd[2 * Bcnt + b]  = surf;
            badp[b]           = s_bad;
        } else {
            atomicAdd(&pd[0], (double)s_ctrl_diff);
            atomicAdd(&pd[1], (double)s_ctrl_mask);
            atomicAdd(&pd[2], surf);
            if (s_bad) atomicOr(badp, 1);
        }
    }
}

__global__ void finalize_partials_kernel(const double* __restrict__ pd,
                                         const int* __restrict__ badp,
                                         float* __restrict__ out, int Bcnt)
{
    __shared__ double sd0[4], sd1[4], sd2[4];
    __shared__ int sb[4];
    const int tid = threadIdx.x;
    double a0 = 0.0, a1 = 0.0, a2 = 0.0; int bad = 0;
    for (int i = tid; i < Bcnt; i += 256) {
        a0 += pd[i]; a1 += pd[Bcnt + i]; a2 += pd[2 * Bcnt + i];
        bad |= badp[i];
    }
    #pragma unroll
    for (int off = 32; off > 0; off >>= 1) {
        a0 += __shfl_down(a0, off);
        a1 += __shfl_down(a1, off);
        a2 += __shfl_down(a2, off);
        bad |= __shfl_down(bad, off);
    }
    if ((tid & 63) == 0) { const int w = tid >> 6; sd0[w] = a0; sd1[w] = a1; sd2[w] = a2; sb[w] = bad; }
    __syncthreads();
    if (tid == 0) {
        double d0 = 0, d1 = 0, d2 = 0; int bb = 0;
        #pragma unroll
        for (int i = 0; i < 4; i++) { d0 += sd0[i]; d1 += sd1[i]; d2 += sd2[i]; bb |= sb[i]; }
        const double denc = d1 * 3.0;
        const double lc = d0 / (denc > 1.0 ? denc : 1.0);
        const double ls = d2 / ((double)Bcnt * OUT_UC * OUT_VC * 3.0);
        out[0] = (float)(lc + ls);            // total (pre-nan-guard, per ref)
        out[1] = (float)lc;                   // loss_ctrl
        out[2] = bb ? 1.0e6f : (float)ls;     // surf_mse with nan/inf guard
    }
}

__global__ void finalize_atomic_kernel(const double* __restrict__ acc,
                                       const int* __restrict__ bad,
                                       float* __restrict__ out, int Bcnt)
{
    const double denc = acc[1] * 3.0;
    const double lc = acc[0] / (denc > 1.0 ? denc : 1.0);
    const double ls = acc[2] / ((double)Bcnt * OUT_UC * OUT_VC * 3.0);
    out[0] = (float)(lc + ls);
    out[1] = (float)lc;
    out[2] = bad[0] ? 1.0e6f : (float)ls;
}

extern "C" void kernel_launch(void* const* d_in, const int* in_sizes, int n_in,
                              void* d_out, int out_size, void* d_ws, size_t ws_size,
                              hipStream_t stream)
{
    const float* pred = (const float*)d_in[0];
    const float* gt   = (const float*)d_in[1];
    const float* mask = (const float*)d_in[2];
    const float* xyz  = (const float*)d_in[3];
    const int Bcnt = in_sizes[2] / (MU_MAXC * MV_MAXC);   // 1024

    double* pd = (double*)d_ws;
    float* out = (float*)d_out;

    const size_t need = (size_t)3 * Bcnt * sizeof(double) + (size_t)Bcnt * sizeof(int);
    if (ws_size >= need) {
        int* badp = (int*)(pd + 3 * Bcnt);
        hipLaunchKernelGGL((nurbs_loss_kernel<0>), dim3(Bcnt), dim3(256), 0, stream,
                           pred, gt, mask, xyz, pd, Bcnt, badp);
        hipLaunchKernelGGL(finalize_partials_kernel, dim3(1), dim3(256), 0, stream,
                           pd, badp, out, Bcnt);
    } else {
        int* badp = (int*)(pd + 3);
        hipLaunchKernelGGL(zero_ws_kernel, dim3(1), dim3(1), 0, stream, pd, badp);
        hipLaunchKernelGGL((nurbs_loss_kernel<1>), dim3(Bcnt), dim3(256), 0, stream,
                           pred, gt, mask, xyz, pd, Bcnt, badp);
        hipLaunchKernelGGL(finalize_atomic_kernel, dim3(1), dim3(1), 0, stream,
                           pd, badp, out, Bcnt);
    }
}